// Round 4
// baseline (697.627 us; speedup 1.0000x reference)
//
#include <hip/hip_runtime.h>

typedef __bf16 bf16x8 __attribute__((ext_vector_type(8)));
typedef float f32x4 __attribute__((ext_vector_type(4)));
typedef unsigned int uintx4 __attribute__((ext_vector_type(4)));

#define PTILE 4096
#define CSRCAP 5120

// ---------- bf16 helpers ----------
__device__ __forceinline__ float bflo(unsigned int u) { return __uint_as_float(u << 16); }
__device__ __forceinline__ float bfhi(unsigned int u) { return __uint_as_float(u & 0xffff0000u); }
__device__ __forceinline__ unsigned int f2bf(float f) {
    unsigned int u = __float_as_uint(f);
    return (u + 0x7fffu + ((u >> 16) & 1u)) >> 16;
}
__device__ __forceinline__ unsigned int pack2(float lo, float hi) {
    return (f2bf(hi) << 16) | f2bf(lo);
}

// ---------- setup ----------
__global__ void k_cvt_w(const float* __restrict__ W1, const float* __restrict__ W2,
                        const float* __restrict__ W3, unsigned short* __restrict__ wb1,
                        unsigned short* __restrict__ wb2, unsigned short* __restrict__ wb3) {
    int i = blockIdx.x * blockDim.x + threadIdx.x;
    if (i < 128 * 128) {
        wb1[i] = (unsigned short)f2bf(W1[i]);
        wb2[i] = (unsigned short)f2bf(W2[i]);
        wb3[i] = (unsigned short)f2bf(W3[i]);
    }
}

__global__ void k_init(int* __restrict__ bktcnt, float* __restrict__ pS,
                       float* __restrict__ pQ, int NB) {
    int t = threadIdx.x;
    if (t < NB) bktcnt[t] = 0;
    for (int i = t; i < 4096; i += 512) { pS[i] = 0.f; pQ[i] = 0.f; }
}

__global__ __launch_bounds__(256) void k_bhist(const int* __restrict__ dst,
                                               int* __restrict__ bktcnt, int E, int NB) {
    __shared__ int h[512];
    for (int i = threadIdx.x; i < NB; i += 256) h[i] = 0;
    __syncthreads();
    for (int e = blockIdx.x * blockDim.x + threadIdx.x; e < E; e += gridDim.x * blockDim.x)
        atomicAdd(&h[dst[e] >> 8], 1);
    __syncthreads();
    for (int i = threadIdx.x; i < NB; i += 256) {
        int c = h[i];
        if (c) atomicAdd(&bktcnt[i], c);
    }
}

__global__ void k_scan(const int* __restrict__ bktcnt, int* __restrict__ bktoff,
                       int* __restrict__ bktcur, int NB) {
    __shared__ int s[512];
    int t = threadIdx.x;
    int v = (t < NB) ? bktcnt[t] : 0;
    s[t] = v;
    __syncthreads();
    for (int off = 1; off < 512; off <<= 1) {
        int a = (t >= off) ? s[t - off] : 0;
        __syncthreads();
        s[t] += a;
        __syncthreads();
    }
    if (t <= NB) {
        int e = s[t] - v;
        bktoff[t] = e;
        if (t < NB) bktcur[t] = e;
    }
}

__global__ __launch_bounds__(256) void k_part(const int* __restrict__ src,
                                              const int* __restrict__ dst,
                                              int* __restrict__ bktcur,
                                              unsigned long long* __restrict__ pairs,
                                              int E, int NB) {
    __shared__ int hist[512], sc[512], base[512], gbase[512];
    __shared__ unsigned long long buf[PTILE];
    int t = threadIdx.x;
    int e0 = blockIdx.x * PTILE;
    int n = min(PTILE, E - e0);

    for (int i = t; i < 512; i += 256) hist[i] = 0;
    __syncthreads();

    int mys[16], myd[16], myb[16], myr[16];
#pragma unroll
    for (int k = 0; k < 16; ++k) {
        int i = t + k * 256;
        bool ok = i < n;
        int d = ok ? dst[e0 + i] : 0;
        int s2 = ok ? src[e0 + i] : 0;
        int b = d >> 8;
        mys[k] = s2; myd[k] = d; myb[k] = b;
        myr[k] = ok ? atomicAdd(&hist[b], 1) : 0;
    }
    __syncthreads();
    sc[t] = hist[t];
    sc[t + 256] = hist[t + 256];
    __syncthreads();
    for (int off = 1; off < 512; off <<= 1) {
        int a = (t >= off) ? sc[t - off] : 0;
        int b2 = (t + 256 >= off) ? sc[t + 256 - off] : 0;
        __syncthreads();
        sc[t] += a;
        sc[t + 256] += b2;
        __syncthreads();
    }
    for (int i = t; i < NB; i += 256) {
        int c = hist[i];
        base[i] = sc[i] - c;
        gbase[i] = c ? atomicAdd(&bktcur[i], c) : 0;
    }
    __syncthreads();
#pragma unroll
    for (int k = 0; k < 16; ++k) {
        int i = t + k * 256;
        if (i < n)
            buf[base[myb[k]] + myr[k]] =
                ((unsigned long long)myd[k] << 32) | (unsigned int)mys[k];
    }
    __syncthreads();
    for (int i = t; i < n; i += 256) {
        unsigned long long p = buf[i];
        int b = (int)(p >> 40);
        pairs[gbase[b] + (i - base[b])] = p;
    }
}

__global__ __launch_bounds__(256) void k_build(const unsigned long long* __restrict__ pairs,
                                               const int* __restrict__ bktoff,
                                               int2* __restrict__ rc,
                                               float* __restrict__ dinv,
                                               int* __restrict__ csr, int N) {
    int b = blockIdx.x, t = threadIdx.x;
    int lo = bktoff[b], hi = bktoff[b + 1], m = hi - lo;
    int node0 = b << 8;
    __shared__ int cnt[256], sc2[256], cur[256];
    __shared__ int csrbuf[CSRCAP];
    cnt[t] = 0;
    __syncthreads();
    for (int i = t; i < m; i += 256) atomicAdd(&cnt[(int)(pairs[lo + i] >> 32) - node0], 1);
    __syncthreads();
    sc2[t] = cnt[t];
    __syncthreads();
    for (int off = 1; off < 256; off <<= 1) {
        int a = (t >= off) ? sc2[t - off] : 0;
        __syncthreads();
        sc2[t] += a;
        __syncthreads();
    }
    int excl = sc2[t] - cnt[t];
    int node = node0 + t;
    if (node < N) {
        rc[node] = make_int2(lo + excl, cnt[t]);
        dinv[node] = rsqrtf((float)cnt[t] + 1.0f);
    }
    cur[t] = excl;
    __syncthreads();
    if (m <= CSRCAP) {
        for (int i = t; i < m; i += 256) {
            unsigned long long p = pairs[lo + i];
            int r = atomicAdd(&cur[(int)(p >> 32) - node0], 1);
            csrbuf[r] = (int)(unsigned int)p;
        }
        __syncthreads();
        for (int i = t; i < m; i += 256) csr[lo + i] = csrbuf[i];
    } else {
        for (int i = t; i < m; i += 256) {
            unsigned long long p = pairs[lo + i];
            int r = atomicAdd(&cur[(int)(p >> 32) - node0], 1);
            csr[lo + r] = (int)(unsigned int)p;
        }
    }
}

// ---------- GEMM: hsS[slice][i][16ch] = (sum_k a[i,k]*W[c,k]) * dinv[i] (slice-major out) ----------
// MODE 0: A = f32 row-major [N][128]; MODE 1: A = bf16 slice-major pre + fused BN/ReLU
template <int MODE>
__global__ __launch_bounds__(256) void k_gemm(const void* __restrict__ Ain,
                                              const unsigned short* __restrict__ Wb,
                                              const float* __restrict__ dinv,
                                              const float* __restrict__ bnA,
                                              const float* __restrict__ bnB,
                                              unsigned short* __restrict__ hs, int N) {
    int wv = threadIdx.x >> 6;
    int lane = threadIdx.x & 63;
    int ln = lane & 15, hi = lane >> 4;
    int rowbase = blockIdx.x * 64 + wv * 16;
    int arow = rowbase + ln;
    bool aok = arow < N;

    bf16x8 a[4];
#pragma unroll
    for (int kc = 0; kc < 4; ++kc) {
        int kb = kc * 32 + hi * 8;
        unsigned int w2[4];
        if (MODE == 0) {
            const float4* Ap = (const float4*)((const float*)Ain + (size_t)arow * 128 + kb);
            float4 f0 = aok ? Ap[0] : make_float4(0.f, 0.f, 0.f, 0.f);
            float4 f1 = aok ? Ap[1] : make_float4(0.f, 0.f, 0.f, 0.f);
            w2[0] = pack2(f0.x, f0.y);
            w2[1] = pack2(f0.z, f0.w);
            w2[2] = pack2(f1.x, f1.y);
            w2[3] = pack2(f1.z, f1.w);
        } else {
            // slice-major A: slice = kb>>4, uint offset within slice-row = (kb>>1)&7
            const uintx4* Ap = (const uintx4*)((const unsigned int*)Ain +
                                               ((size_t)(kb >> 4) * N + arow) * 8 +
                                               ((kb >> 1) & 7));
            uintx4 zz = {0u, 0u, 0u, 0u};
            uintx4 u = aok ? *Ap : zz;
#pragma unroll
            for (int j = 0; j < 4; ++j) {
                int c = kb + 2 * j;
                float lo = fmaxf(bflo(u[j]) * bnA[c] + bnB[c], 0.f);
                float h2 = fmaxf(bfhi(u[j]) * bnA[c + 1] + bnB[c + 1], 0.f);
                w2[j] = pack2(lo, h2);
            }
        }
        uintx4 uu = {w2[0], w2[1], w2[2], w2[3]};
        a[kc] = __builtin_bit_cast(bf16x8, uu);
    }

    float dv[4];
    int er0 = rowbase + hi * 4;
#pragma unroll
    for (int q = 0; q < 4; ++q) dv[q] = (er0 + q < N) ? dinv[er0 + q] : 0.f;

#pragma unroll
    for (int ct = 0; ct < 8; ++ct) {
        int col = ct * 16 + ln;
        const uintx4* Wp = (const uintx4*)(Wb + col * 128 + hi * 8);
        f32x4 acc = {0.f, 0.f, 0.f, 0.f};
#pragma unroll
        for (int kc = 0; kc < 4; ++kc) {
            bf16x8 bfr = __builtin_bit_cast(bf16x8, Wp[kc * 4]);
            acc = __builtin_amdgcn_mfma_f32_16x16x32_bf16(a[kc], bfr, acc, 0, 0, 0);
        }
        // slice-major D-write: slice = ct, within-slice ushort index = ln
#pragma unroll
        for (int q = 0; q < 4; ++q) {
            int r = er0 + q;
            if (r < N) hs[((size_t)ct * N + r) * 16 + ln] = (unsigned short)f2bf(acc[q] * dv[q]);
        }
    }
}

// ---------- gather (slice-major, XCD-resident): slice = blockIdx & 7 ----------
// lane = 1 uint (2 ch) of a 16-ch slice row; 8 lanes/edge, 8 edges/batch.
template <int FINAL>
__global__ __launch_bounds__(256) void k_gather(const unsigned int* __restrict__ hsS,
                                                const int2* __restrict__ rc,
                                                const int* __restrict__ csr,
                                                const float* __restrict__ dinv,
                                                unsigned int* __restrict__ preS,
                                                float* __restrict__ outf,
                                                const float* __restrict__ bias,
                                                float* __restrict__ pS,
                                                float* __restrict__ pQ, int N) {
    int lane = threadIdx.x & 63;
    int wv = threadIdx.x >> 6;
    int slice = blockIdx.x & 7;
    int gblk = blockIdx.x >> 3;
    int w = gblk * 4 + wv;
    int nw = (gridDim.x >> 3) * 4;
    int sub = lane >> 3, cl = lane & 7;
    const unsigned int* hb = hsS + (size_t)slice * N * 8;

    float bx = 0.f, by = 0.f;
    if (FINAL) {
        bx = bias[slice * 16 + 2 * cl];
        by = bias[slice * 16 + 2 * cl + 1];
    }
    float ws0 = 0.f, ws1 = 0.f, wq0 = 0.f, wq1 = 0.f;

    for (int i = w; i < N; i += nw) {
        int2 rcv = rc[i];
        int st = rcv.x, cnt = rcv.y;
        unsigned int us = hb[(size_t)i * 8 + cl];
        float s0 = (sub == 0) ? bflo(us) : 0.f;
        float s1 = (sub == 0) ? bfhi(us) : 0.f;

#define GBATCH(b)                                                   \
    {                                                               \
        int j = ((b) << 3) + sub;                                   \
        bool v = j < cnt;                                           \
        int e = v ? csr[st + j] : 0;                                \
        unsigned int u = v ? hb[(size_t)e * 8 + cl] : 0u;           \
        s0 += bflo(u);                                              \
        s1 += bfhi(u);                                              \
    }
        int nb = (cnt + 7) >> 3;
        if (nb <= 2) {
            GBATCH(0); GBATCH(1);
        } else if (nb <= 4) {
            GBATCH(0); GBATCH(1); GBATCH(2); GBATCH(3);
        } else {
            for (int b = 0; b < nb; ++b) GBATCH(b);
        }
#undef GBATCH

        // reduce across the 8 subgroups (lane bits 3..5)
#pragma unroll
        for (int m = 8; m < 64; m <<= 1) {
            s0 += __shfl_xor(s0, m, 64);
            s1 += __shfl_xor(s1, m, 64);
        }
        float sc = dinv[i];
        s0 *= sc;
        s1 *= sc;

        if (FINAL) {
            if (sub == 0) {
                float2 o;
                o.x = s0 + bx;
                o.y = s1 + by;
                ((float2*)outf)[(size_t)i * 64 + slice * 8 + cl] = o;
            }
        } else {
            if (sub == 0) preS[((size_t)slice * N + i) * 8 + cl] = pack2(s0, s1);
            ws0 += s0; ws1 += s1;
            wq0 += s0 * s0; wq1 += s1 * s1;
        }
    }

    if (!FINAL) {
        __shared__ float red[4][8][4];
        if (sub == 0) {
            red[wv][cl][0] = ws0; red[wv][cl][1] = ws1;
            red[wv][cl][2] = wq0; red[wv][cl][3] = wq1;
        }
        __syncthreads();
        if (threadIdx.x < 8) {
            int c = threadIdx.x;
            float a0 = 0.f, a1 = 0.f, a2 = 0.f, a3 = 0.f;
#pragma unroll
            for (int hh = 0; hh < 4; ++hh) {
                a0 += red[hh][c][0]; a1 += red[hh][c][1];
                a2 += red[hh][c][2]; a3 += red[hh][c][3];
            }
            int base = (gblk & 31) * 128 + slice * 16 + 2 * c;
            atomicAdd(&pS[base], a0);
            atomicAdd(&pS[base + 1], a1);
            atomicAdd(&pQ[base], a2);
            atomicAdd(&pQ[base + 1], a3);
        }
    }
}

__global__ void k_bnfin(const float* __restrict__ g, const float* __restrict__ beta,
                        float* __restrict__ pS, float* __restrict__ pQ,
                        float* __restrict__ bnA, float* __restrict__ bnB, float invN) {
    int c = threadIdx.x;
    if (c < 128) {
        float s = 0.f, q = 0.f;
        for (int k = 0; k < 32; ++k) {
            s += pS[k * 128 + c]; q += pQ[k * 128 + c];
            pS[k * 128 + c] = 0.f; pQ[k * 128 + c] = 0.f;
        }
        float m = s * invN;
        float var = q * invN - m * m;
        float istd = rsqrtf(var + 1e-5f);
        float A = g[c] * istd;
        bnA[c] = A;
        bnB[c] = beta[c] - m * A;
    }
}

// ---------- host ----------
extern "C" void kernel_launch(void* const* d_in, const int* in_sizes, int n_in,
                              void* d_out, int out_size, void* d_ws, size_t ws_size,
                              hipStream_t stream) {
    const float* x = (const float*)d_in[0];
    const int* ei = (const int*)d_in[1];
    const float* W1 = (const float*)d_in[2];
    const float* g1 = (const float*)d_in[4];
    const float* be1 = (const float*)d_in[5];
    const float* W2 = (const float*)d_in[6];
    const float* g2 = (const float*)d_in[8];
    const float* be2 = (const float*)d_in[9];
    const float* W3 = (const float*)d_in[10];
    const float* b3 = (const float*)d_in[11];

    int N = in_sizes[0] / 128;
    int E = in_sizes[1] / 2;
    int NB = (N + 255) >> 8;
    const int* srcp = ei;
    const int* dstp = ei + E;

    char* w = (char*)d_ws;
    auto alloc = [&](size_t b) { char* p = w; w += (b + 255) & ~(size_t)255; return p; };
    int2* rc = (int2*)alloc((size_t)N * 8);
    float* dinv = (float*)alloc((size_t)N * 4);
    int* bktcnt = (int*)alloc(2048);
    int* bktoff = (int*)alloc(2048 + 4);
    int* bktcur = (int*)alloc(2048);
    float* pS = (float*)alloc(4096 * 4);
    float* pQ = (float*)alloc(4096 * 4);
    float* bnA = (float*)alloc(512);
    float* bnB = (float*)alloc(512);
    int* csr = (int*)alloc((size_t)E * 4);
    unsigned long long* pairs = (unsigned long long*)alloc((size_t)E * 8);
    unsigned short* wb1 = (unsigned short*)alloc(16384 * 2);
    unsigned short* wb2 = (unsigned short*)alloc(16384 * 2);
    unsigned short* wb3 = (unsigned short*)alloc(16384 * 2);
    unsigned short* hs = (unsigned short*)alloc((size_t)N * 128 * 2);
    unsigned short* pre = (unsigned short*)alloc((size_t)N * 128 * 2);
    (void)ws_size; (void)n_in; (void)out_size;

    int gemm_grid = (N + 63) / 64;
    int npart = (E + PTILE - 1) / PTILE;
    float invN = 1.0f / (float)N;

    // CSR build
    k_init<<<1, 512, 0, stream>>>(bktcnt, pS, pQ, NB);
    k_cvt_w<<<64, 256, 0, stream>>>(W1, W2, W3, wb1, wb2, wb3);
    k_bhist<<<256, 256, 0, stream>>>(dstp, bktcnt, E, NB);
    k_scan<<<1, 512, 0, stream>>>(bktcnt, bktoff, bktcur, NB);
    k_part<<<npart, 256, 0, stream>>>(srcp, dstp, bktcur, pairs, E, NB);
    k_build<<<NB, 256, 0, stream>>>(pairs, bktoff, rc, dinv, csr, N);

    // layer 1
    k_gemm<0><<<gemm_grid, 256, 0, stream>>>(x, wb1, dinv, nullptr, nullptr, hs, N);
    k_gather<0><<<2048, 256, 0, stream>>>((const unsigned int*)hs, rc, csr, dinv,
                                          (unsigned int*)pre, nullptr, nullptr, pS, pQ, N);
    k_bnfin<<<1, 128, 0, stream>>>(g1, be1, pS, pQ, bnA, bnB, invN);
    // layer 2
    k_gemm<1><<<gemm_grid, 256, 0, stream>>>(pre, wb2, dinv, bnA, bnB, hs, N);
    k_gather<0><<<2048, 256, 0, stream>>>((const unsigned int*)hs, rc, csr, dinv,
                                          (unsigned int*)pre, nullptr, nullptr, pS, pQ, N);
    k_bnfin<<<1, 128, 0, stream>>>(g2, be2, pS, pQ, bnA, bnB, invN);
    // layer 3
    k_gemm<1><<<gemm_grid, 256, 0, stream>>>(pre, wb3, dinv, bnA, bnB, hs, N);
    k_gather<1><<<2048, 256, 0, stream>>>((const unsigned int*)hs, rc, csr, dinv, nullptr,
                                          (float*)d_out, b3, nullptr, nullptr, N);
}

// Round 5
// 464.821 us; speedup vs baseline: 1.5009x; 1.5009x over previous
//
#include <hip/hip_runtime.h>

typedef __bf16 bf16x8 __attribute__((ext_vector_type(8)));
typedef float f32x4 __attribute__((ext_vector_type(4)));
typedef unsigned int uintx4 __attribute__((ext_vector_type(4)));

#define PTILE 4096
#define CSRCAP 5120

// ---------- bf16 helpers ----------
__device__ __forceinline__ float bflo(unsigned int u) { return __uint_as_float(u << 16); }
__device__ __forceinline__ float bfhi(unsigned int u) { return __uint_as_float(u & 0xffff0000u); }
__device__ __forceinline__ unsigned int f2bf(float f) {
    unsigned int u = __float_as_uint(f);
    return (u + 0x7fffu + ((u >> 16) & 1u)) >> 16;
}
__device__ __forceinline__ unsigned int pack2(float lo, float hi) {
    return (f2bf(hi) << 16) | f2bf(lo);
}

// ---------- setup: zero partials + convert weights (merged) ----------
__global__ __launch_bounds__(256) void k_init(const float* __restrict__ W1,
                                              const float* __restrict__ W2,
                                              const float* __restrict__ W3,
                                              unsigned short* __restrict__ wb1,
                                              unsigned short* __restrict__ wb2,
                                              unsigned short* __restrict__ wb3,
                                              float* __restrict__ pS1, float* __restrict__ pQ1,
                                              float* __restrict__ pS2, float* __restrict__ pQ2,
                                              int* __restrict__ bktcnt, int NB) {
    int i = blockIdx.x * blockDim.x + threadIdx.x;
    if (i < 128 * 128) {
        wb1[i] = (unsigned short)f2bf(W1[i]);
        wb2[i] = (unsigned short)f2bf(W2[i]);
        wb3[i] = (unsigned short)f2bf(W3[i]);
        if (i < 4096) { pS1[i] = 0.f; pQ1[i] = 0.f; pS2[i] = 0.f; pQ2[i] = 0.f; }
        if (i < NB) bktcnt[i] = 0;
    }
}

__global__ __launch_bounds__(256) void k_bhist(const int* __restrict__ dst,
                                               int* __restrict__ bktcnt, int E, int NB) {
    __shared__ int h[512];
    for (int i = threadIdx.x; i < NB; i += 256) h[i] = 0;
    __syncthreads();
    for (int e = blockIdx.x * blockDim.x + threadIdx.x; e < E; e += gridDim.x * blockDim.x)
        atomicAdd(&h[dst[e] >> 8], 1);
    __syncthreads();
    for (int i = threadIdx.x; i < NB; i += 256) {
        int c = h[i];
        if (c) atomicAdd(&bktcnt[i], c);
    }
}

__global__ void k_scan(const int* __restrict__ bktcnt, int* __restrict__ bktoff,
                       int* __restrict__ bktcur, int NB) {
    __shared__ int s[512];
    int t = threadIdx.x;
    int v = (t < NB) ? bktcnt[t] : 0;
    s[t] = v;
    __syncthreads();
    for (int off = 1; off < 512; off <<= 1) {
        int a = (t >= off) ? s[t - off] : 0;
        __syncthreads();
        s[t] += a;
        __syncthreads();
    }
    if (t <= NB) {
        int e = s[t] - v;
        bktoff[t] = e;
        if (t < NB) bktcur[t] = e;
    }
}

__global__ __launch_bounds__(256) void k_part(const int* __restrict__ src,
                                              const int* __restrict__ dst,
                                              int* __restrict__ bktcur,
                                              unsigned long long* __restrict__ pairs,
                                              int E, int NB) {
    __shared__ int hist[512], sc[512], base[512], gbase[512];
    __shared__ unsigned long long buf[PTILE];
    int t = threadIdx.x;
    int e0 = blockIdx.x * PTILE;
    int n = min(PTILE, E - e0);

    for (int i = t; i < 512; i += 256) hist[i] = 0;
    __syncthreads();

    int mys[16], myd[16], myb[16], myr[16];
#pragma unroll
    for (int k = 0; k < 16; ++k) {
        int i = t + k * 256;
        bool ok = i < n;
        int d = ok ? dst[e0 + i] : 0;
        int s2 = ok ? src[e0 + i] : 0;
        int b = d >> 8;
        mys[k] = s2; myd[k] = d; myb[k] = b;
        myr[k] = ok ? atomicAdd(&hist[b], 1) : 0;
    }
    __syncthreads();
    sc[t] = hist[t];
    sc[t + 256] = hist[t + 256];
    __syncthreads();
    for (int off = 1; off < 512; off <<= 1) {
        int a = (t >= off) ? sc[t - off] : 0;
        int b2 = (t + 256 >= off) ? sc[t + 256 - off] : 0;
        __syncthreads();
        sc[t] += a;
        sc[t + 256] += b2;
        __syncthreads();
    }
    for (int i = t; i < NB; i += 256) {
        int c = hist[i];
        base[i] = sc[i] - c;
        gbase[i] = c ? atomicAdd(&bktcur[i], c) : 0;
    }
    __syncthreads();
#pragma unroll
    for (int k = 0; k < 16; ++k) {
        int i = t + k * 256;
        if (i < n)
            buf[base[myb[k]] + myr[k]] =
                ((unsigned long long)myd[k] << 32) | (unsigned int)mys[k];
    }
    __syncthreads();
    for (int i = t; i < n; i += 256) {
        unsigned long long p = buf[i];
        int b = (int)(p >> 40);
        pairs[gbase[b] + (i - base[b])] = p;
    }
}

__global__ __launch_bounds__(256) void k_build(const unsigned long long* __restrict__ pairs,
                                               const int* __restrict__ bktoff,
                                               int2* __restrict__ rc,
                                               float* __restrict__ dinv,
                                               int* __restrict__ csr, int N) {
    int b = blockIdx.x, t = threadIdx.x;
    int lo = bktoff[b], hi = bktoff[b + 1], m = hi - lo;
    int node0 = b << 8;
    __shared__ int cnt[256], sc2[256], cur[256];
    __shared__ int csrbuf[CSRCAP];
    cnt[t] = 0;
    __syncthreads();
    for (int i = t; i < m; i += 256) atomicAdd(&cnt[(int)(pairs[lo + i] >> 32) - node0], 1);
    __syncthreads();
    sc2[t] = cnt[t];
    __syncthreads();
    for (int off = 1; off < 256; off <<= 1) {
        int a = (t >= off) ? sc2[t - off] : 0;
        __syncthreads();
        sc2[t] += a;
        __syncthreads();
    }
    int excl = sc2[t] - cnt[t];
    int node = node0 + t;
    if (node < N) {
        rc[node] = make_int2(lo + excl, cnt[t]);
        dinv[node] = rsqrtf((float)cnt[t] + 1.0f);
    }
    cur[t] = excl;
    __syncthreads();
    if (m <= CSRCAP) {
        for (int i = t; i < m; i += 256) {
            unsigned long long p = pairs[lo + i];
            int r = atomicAdd(&cur[(int)(p >> 32) - node0], 1);
            csrbuf[r] = (int)(unsigned int)p;
        }
        __syncthreads();
        for (int i = t; i < m; i += 256) csr[lo + i] = csrbuf[i];
    } else {
        for (int i = t; i < m; i += 256) {
            unsigned long long p = pairs[lo + i];
            int r = atomicAdd(&cur[(int)(p >> 32) - node0], 1);
            csr[lo + r] = (int)(unsigned int)p;
        }
    }
}

// ---------- GEMM: hs[i,c] = (sum_k a[i,k]*W[c,k]) * dinv[i], row-major bf16 out ----------
// MODE 0: A = f32 row-major. MODE 1: A = bf16 pre row-major + fused BN-finalize (from
// partial sums) + BN/ReLU applied during A-load.
template <int MODE>
__global__ __launch_bounds__(256) void k_gemm(const void* __restrict__ Ain,
                                              const unsigned short* __restrict__ Wb,
                                              const float* __restrict__ dinv,
                                              const float* __restrict__ pS,
                                              const float* __restrict__ pQ,
                                              const float* __restrict__ g,
                                              const float* __restrict__ beta, float invN,
                                              unsigned short* __restrict__ hs, int N) {
    __shared__ float sA[128], sB[128];
    if (MODE == 1) {
        int t = threadIdx.x;
        if (t < 128) {
            float s = 0.f, q = 0.f;
#pragma unroll 8
            for (int k = 0; k < 32; ++k) { s += pS[k * 128 + t]; q += pQ[k * 128 + t]; }
            float m = s * invN;
            float var = q * invN - m * m;
            float istd = rsqrtf(var + 1e-5f);
            float A = g[t] * istd;
            sA[t] = A;
            sB[t] = beta[t] - m * A;
        }
        __syncthreads();
    }

    int wv = threadIdx.x >> 6;
    int lane = threadIdx.x & 63;
    int ln = lane & 15, hi = lane >> 4;
    int rowbase = blockIdx.x * 64 + wv * 16;
    int arow = rowbase + ln;
    bool aok = arow < N;

    bf16x8 a[4];
#pragma unroll
    for (int kc = 0; kc < 4; ++kc) {
        int kb = kc * 32 + hi * 8;
        unsigned int w2[4];
        if (MODE == 0) {
            const float4* Ap = (const float4*)((const float*)Ain + (size_t)arow * 128 + kb);
            float4 f0 = aok ? Ap[0] : make_float4(0.f, 0.f, 0.f, 0.f);
            float4 f1 = aok ? Ap[1] : make_float4(0.f, 0.f, 0.f, 0.f);
            w2[0] = pack2(f0.x, f0.y);
            w2[1] = pack2(f0.z, f0.w);
            w2[2] = pack2(f1.x, f1.y);
            w2[3] = pack2(f1.z, f1.w);
        } else {
            const uintx4* Ap =
                (const uintx4*)((const unsigned int*)Ain + (size_t)arow * 64 + (kb >> 1));
            uintx4 zz = {0u, 0u, 0u, 0u};
            uintx4 u = aok ? *Ap : zz;
#pragma unroll
            for (int j = 0; j < 4; ++j) {
                int c = kb + 2 * j;
                float lo = fmaxf(bflo(u[j]) * sA[c] + sB[c], 0.f);
                float h2 = fmaxf(bfhi(u[j]) * sA[c + 1] + sB[c + 1], 0.f);
                w2[j] = pack2(lo, h2);
            }
        }
        uintx4 uu = {w2[0], w2[1], w2[2], w2[3]};
        a[kc] = __builtin_bit_cast(bf16x8, uu);
    }

    float dv[4];
    int er0 = rowbase + hi * 4;
#pragma unroll
    for (int q = 0; q < 4; ++q) dv[q] = (er0 + q < N) ? dinv[er0 + q] : 0.f;

#pragma unroll
    for (int ct = 0; ct < 8; ++ct) {
        int col = ct * 16 + ln;
        const uintx4* Wp = (const uintx4*)(Wb + col * 128 + hi * 8);
        f32x4 acc = {0.f, 0.f, 0.f, 0.f};
#pragma unroll
        for (int kc = 0; kc < 4; ++kc) {
            bf16x8 bfr = __builtin_bit_cast(bf16x8, Wp[kc * 4]);
            acc = __builtin_amdgcn_mfma_f32_16x16x32_bf16(a[kc], bfr, acc, 0, 0, 0);
        }
#pragma unroll
        for (int q = 0; q < 4; ++q) {
            int r = er0 + q;
            if (r < N) hs[(size_t)r * 128 + col] = (unsigned short)f2bf(acc[q] * dv[q]);
        }
    }
}

// ---------- gather (row-major, 2 rows per load instruction) ----------
// Items per node: item 0 = self row, items 1..cnt = csr neighbors.
// Lane half h (lane>>5) handles item 2t+h at step t; lane&31 covers 8 B (4 ch) of the row.
template <int FINAL>
__global__ __launch_bounds__(256) void k_gather(const unsigned int* __restrict__ hs2,
                                                const int2* __restrict__ rc,
                                                const int* __restrict__ csr,
                                                const float* __restrict__ dinv,
                                                unsigned int* __restrict__ pre2,
                                                float* __restrict__ outf,
                                                const float* __restrict__ bias,
                                                float* __restrict__ pS,
                                                float* __restrict__ pQ, int N) {
    int lane = threadIdx.x & 63;
    int wv = threadIdx.x >> 6;
    int hh = lane >> 5, l31 = lane & 31;
    int w = blockIdx.x * 4 + wv;
    int nw = gridDim.x * 4;

    float4 bias4;
    if (FINAL) bias4 = ((const float4*)bias)[l31];
    float ws0 = 0.f, ws1 = 0.f, ws2 = 0.f, ws3 = 0.f;
    float wq0 = 0.f, wq1 = 0.f, wq2 = 0.f, wq3 = 0.f;

    for (int i = w; i < N; i += nw) {
        int2 rcv = rc[i];
        int st = rcv.x, cnt = rcv.y;
        int P = cnt + 1;  // items including self
        float a0 = 0.f, a1 = 0.f, a2 = 0.f, a3 = 0.f;

        if (cnt < 64) {
            int idx = (lane < cnt) ? csr[st + lane] : i;
            int S = (P + 1) >> 1;  // pair-steps, S <= 32
            uint2 u[8];
#pragma unroll
            for (int k = 0; k < 8; ++k) {
                int j = 2 * k + hh;
                int e = __shfl(idx, (j > 0) ? j - 1 : 0, 64);
                if (j == 0) e = i;
                bool v = j < P;
                uint2 t2 = *((const uint2*)(hs2 + (size_t)e * 64) + l31);
                u[k].x = v ? t2.x : 0u;
                u[k].y = v ? t2.y : 0u;
            }
            for (int t = 8; t < S; ++t) {
                uint2 c = u[t & 7];
                a0 += bflo(c.x); a1 += bfhi(c.x);
                a2 += bflo(c.y); a3 += bfhi(c.y);
                int j = 2 * t + hh;
                int e = __shfl(idx, j - 1, 64);
                bool v = j < P;
                uint2 t2 = *((const uint2*)(hs2 + (size_t)e * 64) + l31);
                u[t & 7].x = v ? t2.x : 0u;
                u[t & 7].y = v ? t2.y : 0u;
            }
#pragma unroll
            for (int k = 0; k < 8; ++k) {
                uint2 c = u[k];
                a0 += bflo(c.x); a1 += bfhi(c.x);
                a2 += bflo(c.y); a3 += bfhi(c.y);
            }
        } else {  // generic fallback (cnt >= 64: effectively never)
            for (int j = hh; j < P; j += 2) {
                int e = (j == 0) ? i : csr[st + j - 1];
                uint2 c = *((const uint2*)(hs2 + (size_t)e * 64) + l31);
                a0 += bflo(c.x); a1 += bfhi(c.x);
                a2 += bflo(c.y); a3 += bfhi(c.y);
            }
        }

        // combine the two halves (each channel-quad summed over even+odd items)
        a0 += __shfl_xor(a0, 32, 64);
        a1 += __shfl_xor(a1, 32, 64);
        a2 += __shfl_xor(a2, 32, 64);
        a3 += __shfl_xor(a3, 32, 64);

        float sc = dinv[i];
        a0 *= sc; a1 *= sc; a2 *= sc; a3 *= sc;

        if (FINAL) {
            if (lane < 32) {
                float4 o;
                o.x = a0 + bias4.x;
                o.y = a1 + bias4.y;
                o.z = a2 + bias4.z;
                o.w = a3 + bias4.w;
                ((float4*)outf)[(size_t)i * 32 + l31] = o;
            }
        } else {
            if (lane < 32) {
                uint2 o;
                o.x = pack2(a0, a1);
                o.y = pack2(a2, a3);
                ((uint2*)pre2)[(size_t)i * 32 + l31] = o;
                ws0 += a0; ws1 += a1; ws2 += a2; ws3 += a3;
                wq0 += a0 * a0; wq1 += a1 * a1; wq2 += a2 * a2; wq3 += a3 * a3;
            }
        }
    }

    if (!FINAL) {
        __shared__ float red[4][32][8];
        if (lane < 32) {
            red[wv][l31][0] = ws0; red[wv][l31][1] = ws1;
            red[wv][l31][2] = ws2; red[wv][l31][3] = ws3;
            red[wv][l31][4] = wq0; red[wv][l31][5] = wq1;
            red[wv][l31][6] = wq2; red[wv][l31][7] = wq3;
        }
        __syncthreads();
        int t = threadIdx.x;
        if (t < 128) {  // t = channel c; c = 4*(t>>2) + (t&3)
            int l = t >> 2, q = t & 3;
            float s = red[0][l][q] + red[1][l][q] + red[2][l][q] + red[3][l][q];
            float qq = red[0][l][4 + q] + red[1][l][4 + q] + red[2][l][4 + q] + red[3][l][4 + q];
            int base = ((blockIdx.x & 31) << 7) + t;
            atomicAdd(&pS[base], s);
            atomicAdd(&pQ[base], qq);
        }
    }
}

// ---------- host ----------
extern "C" void kernel_launch(void* const* d_in, const int* in_sizes, int n_in,
                              void* d_out, int out_size, void* d_ws, size_t ws_size,
                              hipStream_t stream) {
    const float* x = (const float*)d_in[0];
    const int* ei = (const int*)d_in[1];
    const float* W1 = (const float*)d_in[2];
    const float* g1 = (const float*)d_in[4];
    const float* be1 = (const float*)d_in[5];
    const float* W2 = (const float*)d_in[6];
    const float* g2 = (const float*)d_in[8];
    const float* be2 = (const float*)d_in[9];
    const float* W3 = (const float*)d_in[10];
    const float* b3 = (const float*)d_in[11];

    int N = in_sizes[0] / 128;
    int E = in_sizes[1] / 2;
    int NB = (N + 255) >> 8;
    const int* srcp = ei;
    const int* dstp = ei + E;

    char* w = (char*)d_ws;
    auto alloc = [&](size_t b) { char* p = w; w += (b + 255) & ~(size_t)255; return p; };
    int2* rc = (int2*)alloc((size_t)N * 8);
    float* dinv = (float*)alloc((size_t)N * 4);
    int* bktcnt = (int*)alloc(2048);
    int* bktoff = (int*)alloc(2048 + 4);
    int* bktcur = (int*)alloc(2048);
    float* pS1 = (float*)alloc(4096 * 4);
    float* pQ1 = (float*)alloc(4096 * 4);
    float* pS2 = (float*)alloc(4096 * 4);
    float* pQ2 = (float*)alloc(4096 * 4);
    int* csr = (int*)alloc((size_t)E * 4);
    unsigned long long* pairs = (unsigned long long*)alloc((size_t)E * 8);
    unsigned short* wb1 = (unsigned short*)alloc(16384 * 2);
    unsigned short* wb2 = (unsigned short*)alloc(16384 * 2);
    unsigned short* wb3 = (unsigned short*)alloc(16384 * 2);
    unsigned short* hs = (unsigned short*)alloc((size_t)N * 128 * 2);
    unsigned short* pre = (unsigned short*)alloc((size_t)N * 128 * 2);
    (void)ws_size; (void)n_in; (void)out_size;

    int gemm_grid = (N + 63) / 64;
    int npart = (E + PTILE - 1) / PTILE;
    float invN = 1.0f / (float)N;

    // CSR build
    k_init<<<64, 256, 0, stream>>>(W1, W2, W3, wb1, wb2, wb3, pS1, pQ1, pS2, pQ2, bktcnt, NB);
    k_bhist<<<256, 256, 0, stream>>>(dstp, bktcnt, E, NB);
    k_scan<<<1, 512, 0, stream>>>(bktcnt, bktoff, bktcur, NB);
    k_part<<<npart, 256, 0, stream>>>(srcp, dstp, bktcur, pairs, E, NB);
    k_build<<<NB, 256, 0, stream>>>(pairs, bktoff, rc, dinv, csr, N);

    // layer 1
    k_gemm<0><<<gemm_grid, 256, 0, stream>>>(x, wb1, dinv, nullptr, nullptr, nullptr, nullptr,
                                             invN, hs, N);
    k_gather<0><<<2048, 256, 0, stream>>>((const unsigned int*)hs, rc, csr, dinv,
                                          (unsigned int*)pre, nullptr, nullptr, pS1, pQ1, N);
    // layer 2 (BN finalize + BN/ReLU fused into GEMM)
    k_gemm<1><<<gemm_grid, 256, 0, stream>>>(pre, wb2, dinv, pS1, pQ1, g1, be1, invN, hs, N);
    k_gather<0><<<2048, 256, 0, stream>>>((const unsigned int*)hs, rc, csr, dinv,
                                          (unsigned int*)pre, nullptr, nullptr, pS2, pQ2, N);
    // layer 3
    k_gemm<1><<<gemm_grid, 256, 0, stream>>>(pre, wb3, dinv, pS2, pQ2, g2, be2, invN, hs, N);
    k_gather<1><<<2048, 256, 0, stream>>>((const unsigned int*)hs, rc, csr, dinv, nullptr,
                                          (float*)d_out, b3, nullptr, nullptr, N);
}

// Round 6
// 367.833 us; speedup vs baseline: 1.8966x; 1.2637x over previous
//
#include <hip/hip_runtime.h>

typedef __bf16 bf16x8 __attribute__((ext_vector_type(8)));
typedef float f32x4 __attribute__((ext_vector_type(4)));
typedef unsigned int uintx4 __attribute__((ext_vector_type(4)));

#define PTILE 4096
#define CSRCAP 5120

// ---------- bf16 helpers ----------
__device__ __forceinline__ float bflo(unsigned int u) { return __uint_as_float(u << 16); }
__device__ __forceinline__ float bfhi(unsigned int u) { return __uint_as_float(u & 0xffff0000u); }
__device__ __forceinline__ unsigned int f2bf(float f) {
    unsigned int u = __float_as_uint(f);
    return (u + 0x7fffu + ((u >> 16) & 1u)) >> 16;
}
__device__ __forceinline__ unsigned int pack2(float lo, float hi) {
    return (f2bf(hi) << 16) | f2bf(lo);
}

// ---------- setup: zero partials + convert weights (merged) ----------
__global__ __launch_bounds__(256) void k_init(const float* __restrict__ W1,
                                              const float* __restrict__ W2,
                                              const float* __restrict__ W3,
                                              unsigned short* __restrict__ wb1,
                                              unsigned short* __restrict__ wb2,
                                              unsigned short* __restrict__ wb3,
                                              float* __restrict__ pS1, float* __restrict__ pQ1,
                                              float* __restrict__ pS2, float* __restrict__ pQ2,
                                              int* __restrict__ bktcnt, int NB) {
    int i = blockIdx.x * blockDim.x + threadIdx.x;
    if (i < 128 * 128) {
        wb1[i] = (unsigned short)f2bf(W1[i]);
        wb2[i] = (unsigned short)f2bf(W2[i]);
        wb3[i] = (unsigned short)f2bf(W3[i]);
        if (i < 4096) { pS1[i] = 0.f; pQ1[i] = 0.f; pS2[i] = 0.f; pQ2[i] = 0.f; }
        if (i < NB) bktcnt[i] = 0;
    }
}

__global__ __launch_bounds__(256) void k_bhist(const int* __restrict__ dst,
                                               int* __restrict__ bktcnt, int E, int NB) {
    __shared__ int h[512];
    for (int i = threadIdx.x; i < NB; i += 256) h[i] = 0;
    __syncthreads();
    for (int e = blockIdx.x * blockDim.x + threadIdx.x; e < E; e += gridDim.x * blockDim.x)
        atomicAdd(&h[dst[e] >> 8], 1);
    __syncthreads();
    for (int i = threadIdx.x; i < NB; i += 256) {
        int c = h[i];
        if (c) atomicAdd(&bktcnt[i], c);
    }
}

__global__ void k_scan(const int* __restrict__ bktcnt, int* __restrict__ bktoff,
                       int* __restrict__ bktcur, int NB) {
    __shared__ int s[512];
    int t = threadIdx.x;
    int v = (t < NB) ? bktcnt[t] : 0;
    s[t] = v;
    __syncthreads();
    for (int off = 1; off < 512; off <<= 1) {
        int a = (t >= off) ? s[t - off] : 0;
        __syncthreads();
        s[t] += a;
        __syncthreads();
    }
    if (t <= NB) {
        int e = s[t] - v;
        bktoff[t] = e;
        if (t < NB) bktcur[t] = e;
    }
}

__global__ __launch_bounds__(256) void k_part(const int* __restrict__ src,
                                              const int* __restrict__ dst,
                                              int* __restrict__ bktcur,
                                              unsigned long long* __restrict__ pairs,
                                              int E, int NB) {
    __shared__ int hist[512], sc[512], base[512], gbase[512];
    __shared__ unsigned long long buf[PTILE];
    int t = threadIdx.x;
    int e0 = blockIdx.x * PTILE;
    int n = min(PTILE, E - e0);

    for (int i = t; i < 512; i += 256) hist[i] = 0;
    __syncthreads();

    int mys[16], myd[16], myb[16], myr[16];
#pragma unroll
    for (int k = 0; k < 16; ++k) {
        int i = t + k * 256;
        bool ok = i < n;
        int d = ok ? dst[e0 + i] : 0;
        int s2 = ok ? src[e0 + i] : 0;
        int b = d >> 8;
        mys[k] = s2; myd[k] = d; myb[k] = b;
        myr[k] = ok ? atomicAdd(&hist[b], 1) : 0;
    }
    __syncthreads();
    sc[t] = hist[t];
    sc[t + 256] = hist[t + 256];
    __syncthreads();
    for (int off = 1; off < 512; off <<= 1) {
        int a = (t >= off) ? sc[t - off] : 0;
        int b2 = (t + 256 >= off) ? sc[t + 256 - off] : 0;
        __syncthreads();
        sc[t] += a;
        sc[t + 256] += b2;
        __syncthreads();
    }
    for (int i = t; i < NB; i += 256) {
        int c = hist[i];
        base[i] = sc[i] - c;
        gbase[i] = c ? atomicAdd(&bktcur[i], c) : 0;
    }
    __syncthreads();
#pragma unroll
    for (int k = 0; k < 16; ++k) {
        int i = t + k * 256;
        if (i < n)
            buf[base[myb[k]] + myr[k]] =
                ((unsigned long long)myd[k] << 32) | (unsigned int)mys[k];
    }
    __syncthreads();
    for (int i = t; i < n; i += 256) {
        unsigned long long p = buf[i];
        int b = (int)(p >> 40);
        pairs[gbase[b] + (i - base[b])] = p;
    }
}

__global__ __launch_bounds__(256) void k_build(const unsigned long long* __restrict__ pairs,
                                               const int* __restrict__ bktoff,
                                               int2* __restrict__ rc,
                                               float* __restrict__ dinv,
                                               int* __restrict__ csr, int N) {
    int b = blockIdx.x, t = threadIdx.x;
    int lo = bktoff[b], hi = bktoff[b + 1], m = hi - lo;
    int node0 = b << 8;
    __shared__ int cnt[256], sc2[256], cur[256];
    __shared__ int csrbuf[CSRCAP];
    cnt[t] = 0;
    __syncthreads();
    for (int i = t; i < m; i += 256) atomicAdd(&cnt[(int)(pairs[lo + i] >> 32) - node0], 1);
    __syncthreads();
    sc2[t] = cnt[t];
    __syncthreads();
    for (int off = 1; off < 256; off <<= 1) {
        int a = (t >= off) ? sc2[t - off] : 0;
        __syncthreads();
        sc2[t] += a;
        __syncthreads();
    }
    int excl = sc2[t] - cnt[t];
    int node = node0 + t;
    if (node < N) {
        rc[node] = make_int2(lo + excl, cnt[t]);
        dinv[node] = rsqrtf((float)cnt[t] + 1.0f);
    }
    cur[t] = excl;
    __syncthreads();
    if (m <= CSRCAP) {
        for (int i = t; i < m; i += 256) {
            unsigned long long p = pairs[lo + i];
            int r = atomicAdd(&cur[(int)(p >> 32) - node0], 1);
            csrbuf[r] = (int)(unsigned int)p;
        }
        __syncthreads();
        for (int i = t; i < m; i += 256) csr[lo + i] = csrbuf[i];
    } else {
        for (int i = t; i < m; i += 256) {
            unsigned long long p = pairs[lo + i];
            int r = atomicAdd(&cur[(int)(p >> 32) - node0], 1);
            csr[lo + r] = (int)(unsigned int)p;
        }
    }
}

// ---------- GEMM: hs[i,c] = (sum_k a[i,k]*W[c,k]) * dinv[i], row-major bf16 out ----------
// MODE 0: A = f32 row-major. MODE 1: A = bf16 pre row-major + fused BN-finalize (from
// partial sums) + BN/ReLU applied during A-load.
template <int MODE>
__global__ __launch_bounds__(256) void k_gemm(const void* __restrict__ Ain,
                                              const unsigned short* __restrict__ Wb,
                                              const float* __restrict__ dinv,
                                              const float* __restrict__ pS,
                                              const float* __restrict__ pQ,
                                              const float* __restrict__ g,
                                              const float* __restrict__ beta, float invN,
                                              unsigned short* __restrict__ hs, int N) {
    __shared__ float sA[128], sB[128];
    if (MODE == 1) {
        int t = threadIdx.x;
        if (t < 128) {
            float s = 0.f, q = 0.f;
#pragma unroll 8
            for (int k = 0; k < 32; ++k) { s += pS[k * 128 + t]; q += pQ[k * 128 + t]; }
            float m = s * invN;
            float var = q * invN - m * m;
            float istd = rsqrtf(var + 1e-5f);
            float A = g[t] * istd;
            sA[t] = A;
            sB[t] = beta[t] - m * A;
        }
        __syncthreads();
    }

    int wv = threadIdx.x >> 6;
    int lane = threadIdx.x & 63;
    int ln = lane & 15, hi = lane >> 4;
    int rowbase = blockIdx.x * 64 + wv * 16;
    int arow = rowbase + ln;
    bool aok = arow < N;

    bf16x8 a[4];
#pragma unroll
    for (int kc = 0; kc < 4; ++kc) {
        int kb = kc * 32 + hi * 8;
        unsigned int w2[4];
        if (MODE == 0) {
            const float4* Ap = (const float4*)((const float*)Ain + (size_t)arow * 128 + kb);
            float4 f0 = aok ? Ap[0] : make_float4(0.f, 0.f, 0.f, 0.f);
            float4 f1 = aok ? Ap[1] : make_float4(0.f, 0.f, 0.f, 0.f);
            w2[0] = pack2(f0.x, f0.y);
            w2[1] = pack2(f0.z, f0.w);
            w2[2] = pack2(f1.x, f1.y);
            w2[3] = pack2(f1.z, f1.w);
        } else {
            const uintx4* Ap =
                (const uintx4*)((const unsigned int*)Ain + (size_t)arow * 64 + (kb >> 1));
            uintx4 zz = {0u, 0u, 0u, 0u};
            uintx4 u = aok ? *Ap : zz;
#pragma unroll
            for (int j = 0; j < 4; ++j) {
                int c = kb + 2 * j;
                float lo = fmaxf(bflo(u[j]) * sA[c] + sB[c], 0.f);
                float h2 = fmaxf(bfhi(u[j]) * sA[c + 1] + sB[c + 1], 0.f);
                w2[j] = pack2(lo, h2);
            }
        }
        uintx4 uu = {w2[0], w2[1], w2[2], w2[3]};
        a[kc] = __builtin_bit_cast(bf16x8, uu);
    }

    float dv[4];
    int er0 = rowbase + hi * 4;
#pragma unroll
    for (int q = 0; q < 4; ++q) dv[q] = (er0 + q < N) ? dinv[er0 + q] : 0.f;

#pragma unroll
    for (int ct = 0; ct < 8; ++ct) {
        int col = ct * 16 + ln;
        const uintx4* Wp = (const uintx4*)(Wb + col * 128 + hi * 8);
        f32x4 acc = {0.f, 0.f, 0.f, 0.f};
#pragma unroll
        for (int kc = 0; kc < 4; ++kc) {
            bf16x8 bfr = __builtin_bit_cast(bf16x8, Wp[kc * 4]);
            acc = __builtin_amdgcn_mfma_f32_16x16x32_bf16(a[kc], bfr, acc, 0, 0, 0);
        }
#pragma unroll
        for (int q = 0; q < 4; ++q) {
            int r = er0 + q;
            if (r < N) hs[(size_t)r * 128 + col] = (unsigned short)f2bf(acc[q] * dv[q]);
        }
    }
}

// ---------- gather (R3 structure: whole-row loads, readlane idx broadcast, 8-deep ring) ----------
template <int FINAL>
__global__ __launch_bounds__(256) void k_gather(const unsigned int* __restrict__ hs2,
                                                const int2* __restrict__ rc,
                                                const int* __restrict__ csr,
                                                const float* __restrict__ dinv,
                                                unsigned int* __restrict__ pre2,
                                                float* __restrict__ outf,
                                                const float* __restrict__ bias,
                                                float* __restrict__ pS,
                                                float* __restrict__ pQ, int N) {
    int lane = threadIdx.x & 63;
    int wv = threadIdx.x >> 6;
    int w = blockIdx.x * 4 + wv;
    int nw = gridDim.x * 4;
    float ws0 = 0.f, ws1 = 0.f, wq0 = 0.f, wq1 = 0.f;

    for (int i = w; i < N; i += nw) {
        int2 rcv = rc[i];
        int st = rcv.x, cnt = rcv.y;
        unsigned int us = hs2[(size_t)i * 64 + lane];
        float s0 = bflo(us), s1 = bfhi(us);

        if (cnt <= 64) {
            int idx = (lane < cnt) ? csr[st + lane] : 0;
            int nfull = cnt & ~7;
            if (nfull) {
                int e[8];
                unsigned int u[8];
#pragma unroll
                for (int k = 0; k < 8; ++k) e[k] = __shfl(idx, k, 64);
#pragma unroll
                for (int k = 0; k < 8; ++k) u[k] = hs2[(size_t)e[k] * 64 + lane];
                for (int j = 8; j < nfull; j += 8) {
                    int en[8];
                    unsigned int un[8];
#pragma unroll
                    for (int k = 0; k < 8; ++k) en[k] = __shfl(idx, j + k, 64);
#pragma unroll
                    for (int k = 0; k < 8; ++k) un[k] = hs2[(size_t)en[k] * 64 + lane];
#pragma unroll
                    for (int k = 0; k < 8; ++k) { s0 += bflo(u[k]); s1 += bfhi(u[k]); }
#pragma unroll
                    for (int k = 0; k < 8; ++k) u[k] = un[k];
                }
#pragma unroll
                for (int k = 0; k < 8; ++k) { s0 += bflo(u[k]); s1 += bfhi(u[k]); }
            }
            for (int j = nfull; j < cnt; ++j) {
                int e0 = __shfl(idx, j, 64);
                unsigned int u = hs2[(size_t)e0 * 64 + lane];
                s0 += bflo(u);
                s1 += bfhi(u);
            }
        } else {  // generic fallback (cnt > 64: effectively never for this graph)
            for (int j = 0; j < cnt; ++j) {
                unsigned int u = hs2[(size_t)csr[st + j] * 64 + lane];
                s0 += bflo(u);
                s1 += bfhi(u);
            }
        }

        float sc = dinv[i];
        s0 *= sc;
        s1 *= sc;
        if (FINAL) {
            float2 o;
            o.x = s0 + bias[2 * lane];
            o.y = s1 + bias[2 * lane + 1];
            ((float2*)outf)[(size_t)i * 64 + lane] = o;
        } else {
            pre2[(size_t)i * 64 + lane] = pack2(s0, s1);
            ws0 += s0; ws1 += s1;
            wq0 += s0 * s0; wq1 += s1 * s1;
        }
    }

    if (!FINAL) {
        __shared__ float red[4][64][4];
        red[wv][lane][0] = ws0; red[wv][lane][1] = ws1;
        red[wv][lane][2] = wq0; red[wv][lane][3] = wq1;
        __syncthreads();
        if (wv == 0) {
#pragma unroll
            for (int hh = 1; hh < 4; ++hh) {
                ws0 += red[hh][lane][0]; ws1 += red[hh][lane][1];
                wq0 += red[hh][lane][2]; wq1 += red[hh][lane][3];
            }
            int slot = (blockIdx.x & 31) * 128;
            atomicAdd(&pS[slot + 2 * lane], ws0);
            atomicAdd(&pS[slot + 2 * lane + 1], ws1);
            atomicAdd(&pQ[slot + 2 * lane], wq0);
            atomicAdd(&pQ[slot + 2 * lane + 1], wq1);
        }
    }
}

// ---------- host ----------
extern "C" void kernel_launch(void* const* d_in, const int* in_sizes, int n_in,
                              void* d_out, int out_size, void* d_ws, size_t ws_size,
                              hipStream_t stream) {
    const float* x = (const float*)d_in[0];
    const int* ei = (const int*)d_in[1];
    const float* W1 = (const float*)d_in[2];
    const float* g1 = (const float*)d_in[4];
    const float* be1 = (const float*)d_in[5];
    const float* W2 = (const float*)d_in[6];
    const float* g2 = (const float*)d_in[8];
    const float* be2 = (const float*)d_in[9];
    const float* W3 = (const float*)d_in[10];
    const float* b3 = (const float*)d_in[11];

    int N = in_sizes[0] / 128;
    int E = in_sizes[1] / 2;
    int NB = (N + 255) >> 8;
    const int* srcp = ei;
    const int* dstp = ei + E;

    char* w = (char*)d_ws;
    auto alloc = [&](size_t b) { char* p = w; w += (b + 255) & ~(size_t)255; return p; };
    int2* rc = (int2*)alloc((size_t)N * 8);
    float* dinv = (float*)alloc((size_t)N * 4);
    int* bktcnt = (int*)alloc(2048);
    int* bktoff = (int*)alloc(2048 + 4);
    int* bktcur = (int*)alloc(2048);
    float* pS1 = (float*)alloc(4096 * 4);
    float* pQ1 = (float*)alloc(4096 * 4);
    float* pS2 = (float*)alloc(4096 * 4);
    float* pQ2 = (float*)alloc(4096 * 4);
    int* csr = (int*)alloc((size_t)E * 4);
    unsigned long long* pairs = (unsigned long long*)alloc((size_t)E * 8);
    unsigned short* wb1 = (unsigned short*)alloc(16384 * 2);
    unsigned short* wb2 = (unsigned short*)alloc(16384 * 2);
    unsigned short* wb3 = (unsigned short*)alloc(16384 * 2);
    unsigned short* hs = (unsigned short*)alloc((size_t)N * 128 * 2);
    unsigned short* pre = (unsigned short*)alloc((size_t)N * 128 * 2);
    (void)ws_size; (void)n_in; (void)out_size;

    int gemm_grid = (N + 63) / 64;
    int npart = (E + PTILE - 1) / PTILE;
    float invN = 1.0f / (float)N;

    // CSR build
    k_init<<<64, 256, 0, stream>>>(W1, W2, W3, wb1, wb2, wb3, pS1, pQ1, pS2, pQ2, bktcnt, NB);
    k_bhist<<<256, 256, 0, stream>>>(dstp, bktcnt, E, NB);
    k_scan<<<1, 512, 0, stream>>>(bktcnt, bktoff, bktcur, NB);
    k_part<<<npart, 256, 0, stream>>>(srcp, dstp, bktcur, pairs, E, NB);
    k_build<<<NB, 256, 0, stream>>>(pairs, bktoff, rc, dinv, csr, N);

    // layer 1
    k_gemm<0><<<gemm_grid, 256, 0, stream>>>(x, wb1, dinv, nullptr, nullptr, nullptr, nullptr,
                                             invN, hs, N);
    k_gather<0><<<2048, 256, 0, stream>>>((const unsigned int*)hs, rc, csr, dinv,
                                          (unsigned int*)pre, nullptr, nullptr, pS1, pQ1, N);
    // layer 2 (BN finalize + BN/ReLU fused into GEMM)
    k_gemm<1><<<gemm_grid, 256, 0, stream>>>(pre, wb2, dinv, pS1, pQ1, g1, be1, invN, hs, N);
    k_gather<0><<<2048, 256, 0, stream>>>((const unsigned int*)hs, rc, csr, dinv,
                                          (unsigned int*)pre, nullptr, nullptr, pS2, pQ2, N);
    // layer 3
    k_gemm<1><<<gemm_grid, 256, 0, stream>>>(pre, wb3, dinv, pS2, pQ2, g2, be2, invN, hs, N);
    k_gather<1><<<2048, 256, 0, stream>>>((const unsigned int*)hs, rc, csr, dinv, nullptr,
                                          (float*)d_out, b3, nullptr, nullptr, N);
}